// Round 5
// baseline (259.034 us; speedup 1.0000x reference)
//
#include <hip/hip_runtime.h>
#include <stdint.h>

#define B_ 4
#define T_ 2048
#define C_ 1024
#define H_ 16
#define D_ 64
#define M_ (B_*T_)      /* 8192 */
#define K_ C_           /* 1024 */

typedef unsigned short ushort_t;
typedef __bf16 bf16x8 __attribute__((ext_vector_type(8)));
typedef float  float4_ __attribute__((ext_vector_type(4)));
typedef ushort_t ushort4_ __attribute__((ext_vector_type(4)));
typedef uint32_t uint32x2 __attribute__((ext_vector_type(2)));

__device__ __forceinline__ ushort_t f2bf(float f) {
    union { float f; uint32_t u; } c; c.f = f;
    uint32_t u = c.u;
    uint32_t r = (u + 0x7FFFu + ((u >> 16) & 1u)) >> 16;
    return (ushort_t)r;
}
__device__ __forceinline__ float4_ f4zero() { float4_ z; z[0]=0.f; z[1]=0.f; z[2]=0.f; z[3]=0.f; return z; }

// packed f32x2 -> bf16x2 (single HW instr; no builtin on gfx950 — T12 recipe)
__device__ __forceinline__ uint32_t cvtpk(float a, float b) {
    uint32_t r;
    asm("v_cvt_pk_bf16_f32 %0, %1, %2" : "=v"(r) : "v"(a), "v"(b));
    return r;
}

// async global->LDS, 16B per lane; LDS dest must be wave-uniform base + lane*16
#define GLDS16(gptr, lptr) \
    __builtin_amdgcn_global_load_lds((const __attribute__((address_space(1))) uint32_t*)(gptr), \
                                     (__attribute__((address_space(3))) uint32_t*)(lptr), 16, 0, 0)

// raw barrier / counted waits (NEVER __syncthreads in the pipelined GEMM —
// it drains vmcnt(0) and kills the in-flight prefetch)
#define BARRIER() asm volatile("s_barrier" ::: "memory")
#define VMCNT(n)  asm volatile("s_waitcnt vmcnt(" #n ")" ::: "memory")

// ---------------------------------------------------------------------------
// f32 -> bf16 conversion, 4 elements/thread
// ---------------------------------------------------------------------------
__global__ __launch_bounds__(256) void cvt_f32_bf16(const float* __restrict__ src,
                                                    ushort_t* __restrict__ dst) {
    const int i = (blockIdx.x * 256 + threadIdx.x) * 4;
    float4_ v = *(const float4_*)(src + i);
    ushort4_ o;
    #pragma unroll
    for (int e = 0; e < 4; e++) o[e] = f2bf(v[e]);
    *(ushort4_*)(dst + i) = o;
}

// fused 3-matrix cvt: wq|wk|wv (1M elements each) -> wcat [3072][1024]
__global__ __launch_bounds__(256) void cvt3_f32_bf16(const float* __restrict__ s0,
                                                     const float* __restrict__ s1,
                                                     const float* __restrict__ s2,
                                                     ushort_t* __restrict__ dst) {
    const int b = blockIdx.x;                       // 0..3071
    const float* src = (b < 1024) ? s0 : (b < 2048) ? s1 : s2;
    const int off = (b & 1023) * 1024 + threadIdx.x * 4;
    float4_ v = *(const float4_*)(src + off);
    ushort4_ o;
    #pragma unroll
    for (int e = 0; e < 4; e++) o[e] = f2bf(v[e]);
    *(ushort4_*)(dst + (size_t)b * 1024 + threadIdx.x * 4) = o;
}

// ---------------------------------------------------------------------------
// w_o f32 [1024(hd)][1024(c)] -> wot bf16 [1024(c)][1024(hd)]
// ---------------------------------------------------------------------------
__global__ __launch_bounds__(256) void transpose_wo(const float* __restrict__ wo,
                                                    ushort_t* __restrict__ wot) {
    __shared__ ushort_t tile[64][65];
    const int c0 = (blockIdx.x & 15) * 64;
    const int r0 = (blockIdx.x >> 4) * 64;   // hd tile base
    const int tid = threadIdx.x;
    const int row = tid >> 2;                // 64 rows, 4 threads/row
    const int col = (tid & 3) * 16;
    #pragma unroll
    for (int r = 0; r < 4; r++) {
        float4_ v = *(const float4_*)(wo + (size_t)(r0 + row) * 1024 + c0 + col + r * 4);
        #pragma unroll
        for (int e = 0; e < 4; e++) tile[row][col + r * 4 + e] = f2bf(v[e]);
    }
    __syncthreads();
    #pragma unroll
    for (int r = 0; r < 2; r++) {
        bf16x8 v;
        #pragma unroll
        for (int e = 0; e < 8; e++) v[e] = __builtin_bit_cast(__bf16, tile[col + r * 8 + e][row]);
        *(bf16x8*)(wot + (size_t)(c0 + row) * 1024 + r0 + col + r * 8) = v;
    }
}

// ---------------------------------------------------------------------------
// 8-phase-style pipelined GEMM (T2+T3+T4+T5): C[M x N] = A[M x K] * Bt[N x K]^T
//   BM=256, BN=128, BK=64, 8 waves (4M x 2N), per-wave 64x64 (acc[4][4]).
// LDS 96 KB: A [2 buf][2 half][128 lr][64], B [2 buf][128][64], XOR-swizzled
//   (linear glds dest + inverse-swizzled global source + swizzled ds_read).
// Per iter (2 K-tiles; buf0=even, buf1=odd), 4 phases of
//   {ds_read frags | issue half-tile prefetch | BAR | 16 MFMA (setprio) | BAR}
//   counted vmcnt(2) gates ONLY at tile boundaries. Ledger (audited r4):
//   GATE_B drains {A10,A11,B1}(odd tile), S3 may fly; GATE_A drains
//   {A00,A01,B0}(even+2), S6 may fly. Tail = full iteration minus
//   next-tile prefetches; vmcnt(0) before computing tile NT-1.  <-- r4 FIX:
//   previous version never staged A1/B of the last tile (read stale data).
// ---------------------------------------------------------------------------
template<int MODE>
__global__ __launch_bounds__(512, 2)
void gemm8(const ushort_t* __restrict__ A,
           const ushort_t* __restrict__ Bt,
           ushort_t* __restrict__ q_ws, ushort_t* __restrict__ k_ws,
           ushort_t* __restrict__ vt_ws, float* __restrict__ outp)
{
    __shared__ __align__(16) ushort_t As8[2][2][128 * 64];  // [buf][half][lr][64] 64 KB
    __shared__ __align__(16) ushort_t Bs8[2][128 * 64];     // [buf][row][64]      32 KB
    const int tid = threadIdx.x;
    const int m0 = blockIdx.x * 256;
    const int n0 = blockIdx.y * 128;
    const int L = tid & 63, wid = tid >> 6;
    const int wm = wid >> 1;          // 0..3 (M)
    const int wn = wid & 1;           // 0..1 (N)
    const int quad = L >> 4, lc = L & 15;

    // ---- staging addressing: 2 chunks of 8 KB (512 thr x 16 B) per half-tile
    // LDS dest linear; global SOURCE carries the inverse XOR swizzle (rule #21)
    size_t a_src[2], b_src[2];
    int    l_off[2];
    #pragma unroll
    for (int q = 0; q < 2; q++) {
        const int off = tid * 16 + q * 8192;
        const int lr = off >> 7, slot = (off >> 4) & 7;
        const int sp = slot ^ (lr & 7);
        l_off[q] = off;
        // A half-row map: global row = (lr>>5)*64 + h*32 + (lr&31)  (h added later)
        a_src[q] = (size_t)(m0 + (lr >> 5) * 64 + (lr & 31)) * 2048 + sp * 16;
        b_src[q] = (size_t)(n0 + lr) * 2048 + sp * 16;
    }
    const char* Ag = (const char*)A;
    const char* Bg = (const char*)Bt;

    auto STAGE_A = [&](int c, int h, int kt) {
        #pragma unroll
        for (int q = 0; q < 2; q++)
            GLDS16(Ag + a_src[q] + (size_t)h * 65536 + (size_t)kt * 128,
                   (char*)As8[c][h] + l_off[q]);
    };
    auto STAGE_B = [&](int c, int kt) {
        #pragma unroll
        for (int q = 0; q < 2; q++)
            GLDS16(Bg + b_src[q] + (size_t)kt * 128, (char*)Bs8[c] + l_off[q]);
    };

    // ---- swizzled fragment read offsets (loop-invariant)
    int offA[2][2], offB[4][2];   // [mi2][ks], [nj][ks]
    #pragma unroll
    for (int mi2 = 0; mi2 < 2; mi2++)
        #pragma unroll
        for (int ks = 0; ks < 2; ks++) {
            const int lr = wm * 32 + mi2 * 16 + lc;
            offA[mi2][ks] = lr * 128 + (((ks * 4 + quad) ^ (lc & 7)) << 4);
        }
    #pragma unroll
    for (int nj = 0; nj < 4; nj++)
        #pragma unroll
        for (int ks = 0; ks < 2; ks++) {
            const int row = wn * 64 + nj * 16 + lc;
            offB[nj][ks] = row * 128 + (((ks * 4 + quad) ^ (lc & 7)) << 4);
        }

    float4_ acc[4][4];
    #pragma unroll
    for (int i = 0; i < 4; i++)
        #pragma unroll
        for (int j = 0; j < 4; j++) acc[i][j] = f4zero();

#define LOAD_AF(AF, c, h) \
    _Pragma("unroll") for (int mi2_ = 0; mi2_ < 2; mi2_++) \
    _Pragma("unroll") for (int ks_ = 0; ks_ < 2; ks_++) \
        AF[mi2_][ks_] = *(const bf16x8*)((const char*)As8[c][h] + offA[mi2_][ks_]);
#define LOAD_BF(c) \
    _Pragma("unroll") for (int nj_ = 0; nj_ < 4; nj_++) \
    _Pragma("unroll") for (int ks_ = 0; ks_ < 2; ks_++) \
        bfr[nj_][ks_] = *(const bf16x8*)((const char*)Bs8[c] + offB[nj_][ks_]);
#define PHASE_MFMA(AF, MB) \
    __builtin_amdgcn_s_setprio(1); \
    _Pragma("unroll") for (int mi2_ = 0; mi2_ < 2; mi2_++) \
    _Pragma("unroll") for (int nj_ = 0; nj_ < 4; nj_++) { \
        acc[(MB) + mi2_][nj_] = __builtin_amdgcn_mfma_f32_16x16x32_bf16(AF[mi2_][0], bfr[nj_][0], acc[(MB) + mi2_][nj_], 0, 0, 0); \
        acc[(MB) + mi2_][nj_] = __builtin_amdgcn_mfma_f32_16x16x32_bf16(AF[mi2_][1], bfr[nj_][1], acc[(MB) + mi2_][nj_], 0, 0, 0); \
    } \
    __builtin_amdgcn_s_setprio(0);

    // ---- prologue: tile0 complete + A0(1) in flight
    STAGE_A(0, 0, 0);
    STAGE_A(0, 1, 0);
    STAGE_B(0, 0);
    STAGE_A(1, 0, 1);
    VMCNT(2);
    BARRIER();

    bf16x8 bfr[4][2];
    bf16x8 af0[2][2], af1[2][2];

    // NT=16 K-tiles, 2 per iter; main loop 7 iters (all stages in-bounds)
    for (int i = 0; i < 7; i++) {
        const int kt1 = 2 * i + 1;
        // P0: buf0.half0 + buf0.B
        LOAD_AF(af0, 0, 0);
        LOAD_BF(0);
        STAGE_A(1, 1, kt1);             // S1: A1(odd) -> buf1 (last read prev P3)
        BARRIER();
        PHASE_MFMA(af0, 0);
        BARRIER();
        // P1: buf0.half1
        LOAD_AF(af1, 0, 1);
        STAGE_B(1, kt1);                // S2: B(odd) -> buf1
        STAGE_A(0, 0, kt1 + 1);         // S3: A0(even+2) -> buf0 (freed by P0)
        BARRIER();
        PHASE_MFMA(af1, 2);
        VMCNT(2);                       // GATE_B: odd tile staged (S3 may fly)
        BARRIER();
        // P2: buf1.half0 + buf1.B
        LOAD_AF(af0, 1, 0);
        LOAD_BF(1);
        STAGE_A(0, 1, kt1 + 1);         // S4: A1(even+2) -> buf0 (freed by P1)
        BARRIER();
        PHASE_MFMA(af0, 0);
        BARRIER();
        // P3: buf1.half1
        LOAD_AF(af1, 1, 1);
        STAGE_B(0, kt1 + 1);            // S5: B(even+2) -> buf0
        STAGE_A(1, 0, kt1 + 2);         // S6: A0(odd+2) -> buf1 (freed by P2)
        BARRIER();
        PHASE_MFMA(af1, 2);
        VMCNT(2);                       // GATE_A: next even tile staged (S6 may fly)
        BARRIER();
    }
    // ---- tail iter (tiles 14,15): stage tile 15's remaining halves, no tile-16
    // (r4 FIX: previous tail omitted S1/S2 -> read stale A1/B for tile 15)
    LOAD_AF(af0, 0, 0);                 // tP0: tile14 half0 + B (staged by GATE_A)
    LOAD_BF(0);
    STAGE_A(1, 1, 15);                  // S1: A1(15) -> buf1
    BARRIER();
    PHASE_MFMA(af0, 0);
    BARRIER();
    LOAD_AF(af1, 0, 1);                 // tP1: tile14 half1
    STAGE_B(1, 15);                     // S2: B(15) -> buf1
    BARRIER();
    PHASE_MFMA(af1, 2);
    VMCNT(0);                           // GATE (tail): A0(15)[S6], A1(15), B(15) landed
    BARRIER();
    LOAD_AF(af0, 1, 0);                 // tP2: tile15 half0 + B
    LOAD_BF(1);
    BARRIER();
    PHASE_MFMA(af0, 0);
    BARRIER();
    LOAD_AF(af1, 1, 1);                 // tP3: tile15 half1
    BARRIER();
    PHASE_MFMA(af1, 2);

#undef LOAD_AF
#undef LOAD_BF
#undef PHASE_MFMA

    // ---- epilogue: C/D layout col=lane&15, row=quad*4+reg (m89-verified)
    const int mat = n0 >> 10;          // MODE 0: which of q/k/v
    const int nb  = n0 & 1023;
    const int wr  = wm * 64;
    const int wc  = wn * 64;
    #pragma unroll
    for (int i = 0; i < 4; i++) {
        #pragma unroll
        for (int j = 0; j < 4; j++) {
            #pragma unroll
            for (int rg = 0; rg < 4; rg++) {
                const int mg = m0 + wr + i * 16 + quad * 4 + rg;
                const float v = acc[i][j][rg];
                if (MODE == 1) {
                    const int cg = n0 + wc + j * 16 + lc;
                    outp[(size_t)mg * 1024 + cg] = v;          // f32 store
                } else {
                    const int ln = nb + wc + j * 16 + lc;
                    const int h = ln >> 6, d = ln & 63;
                    const int n = mg >> 11, t = mg & 2047;
                    const int nh = n * H_ + h;
                    // 0.125 * log2(e): softmax computed with exp2 (saves 1 mul/score)
                    if (mat == 0)      q_ws [((size_t)nh * T_ + t) * 64 + d] = f2bf(v * 0.18033688011112042f);
                    else if (mat == 1) k_ws [((size_t)nh * T_ + t) * 64 + d] = f2bf(v);
                    else               vt_ws[((size_t)nh * 64 + d) * T_ + t] = f2bf(v);
                }
            }
        }
    }
}

// ---------------------------------------------------------------------------
// MFMA flash attention, transposed formulation (round-3, validated):
//   S^T = K Q^T ; O^T = V^T P^T ; per-lane scalar softmax state (exp2 domain).
//   Global heavy-first dispatch + XCD-local nh mapping.
// ---------------------------------------------------------------------------
#define KP 72   /* Ps padded row pitch, elements (P path only) */

__global__ __launch_bounds__(512)
void attn(const ushort_t* __restrict__ q_ws, const ushort_t* __restrict__ k_ws,
          const ushort_t* __restrict__ vt_ws, ushort_t* __restrict__ y_ws)
{
    __shared__ __align__(16) ushort_t Ks[2][64 * 64];   // [s][d] 128B pitch, swizzled
    __shared__ __align__(16) ushort_t Vs[2][64 * 64];   // [d][s] 128B pitch, swizzled
    __shared__ __align__(16) ushort_t Ps[8][16 * KP];   // per-wave P^T as [t][s]
    const int tid  = threadIdx.x;
    const int L    = tid & 63;
    const int w    = tid >> 6;           // 0..7
    const int quad = L >> 4, lc = L & 15;
    const int bid  = blockIdx.x;
    const int qt   = 15 - (bid >> 6);    // GLOBAL heavy-first: qt=15 blocks first
    const int nh   = bid & 63;           // bid%8 == nh%8 -> XCD-local K/V
    const int n    = nh >> 4;
    const int tq0  = qt * 128 + w * 16;
    const int tg   = tq0 + lc;           // this lane's q-row
    const int nt   = 2 * qt + 2;         // K/V 64-tiles this block touches
    const int dstile = tq0 >> 6;         // first tile needing the causal mask

    // Q fragments (B-operand layout [n=t=lc][k=d=quad*8+j]):
    const ushort_t* qbase = q_ws + ((size_t)nh * T_ + tq0) * 64;
    const bf16x8 qf0 = *(const bf16x8*)(qbase + (size_t)lc * 64 + quad * 8);
    const bf16x8 qf1 = *(const bf16x8*)(qbase + (size_t)lc * 64 + quad * 8 + 32);

    float m_i = -1e30f, l_i = 0.f;       // per-lane scalars (q-row tg), log2 domain
    float4_ o[4];                        // O^T C-layout: col=t (lane), row=d
    #pragma unroll
    for (int r = 0; r < 4; r++) o[r] = f4zero();

    const char* kbase = (const char*)(k_ws  + (size_t)nh * T_ * 64);   // [t][d]
    const char* vbase = (const char*)(vt_ws + (size_t)nh * 64 * T_);   // [d][t]
    char* pwr = (char*)Ps[w] + lc * (KP * 2);

    // staging: 512 threads x 16B = one 8KB tile per glds instruction.
    const int ldsoff = tid * 16;                 // linear byte offset in 8KB buffer
    const int srow   = ldsoff >> 7;              // 0..63
    const int sslot  = (ldsoff >> 4) & 7;
    const int sgs    = sslot ^ (srow & 7);       // inverse swizzle on SOURCE
    const size_t kgo = (size_t)srow * 128 + sgs * 16;
    const size_t vgo = (size_t)srow * (T_ * 2) + sgs * 16;

    // loop-invariant swizzled read offsets (rows b*16+lc, 16B slots quad/quad+4)
    int off16[4][2];
    #pragma unroll
    for (int b = 0; b < 4; b++) {
        const int row = b * 16 + lc;
        const int r7  = lc & 7;                  // (b*16+lc)&7 == lc&7
        off16[b][0] = row * 128 + ((quad ^ r7) << 4);
        off16[b][1] = row * 128 + (((quad + 4) ^ r7) << 4);
    }

    auto STAGE = [&](int st, int b) {
        GLDS16(kbase + (size_t)st * 8192 + kgo, (char*)Ks[b] + ldsoff);
        GLDS16(vbase + (size_t)st * 128  + vgo, (char*)Vs[b] + ldsoff);
    };

    STAGE(0, 0);
    __syncthreads();                      // drains vmcnt(0): buf0 staged
    int cur = 0;

    for (int st = 0; st < nt; st++) {
        if (st + 1 < nt) STAGE(st + 1, cur ^ 1);   // prefetch overlaps compute
        // wave-uniform skip of fully-masked final tile (lower-half waves)
        if (st * 64 <= tq0 + 15) {
            const char* ks = (const char*)Ks[cur];
            const char* vs = (const char*)Vs[cur];

            // S^T = K Q^T: 4 s-blocks of 16; D[s][t]: row=quad*4+rg, col=lc
            float4_ s[4];
            #pragma unroll
            for (int sb = 0; sb < 4; sb++) {
                const bf16x8 kf0 = *(const bf16x8*)(ks + off16[sb][0]);
                const bf16x8 kf1 = *(const bf16x8*)(ks + off16[sb][1]);
                float4_ a = f4zero();
                a = __builtin_amdgcn_mfma_f32_16x16x32_bf16(kf0, qf0, a, 0, 0, 0);
                a = __builtin_amdgcn_mfma_f32_16x16x32_bf16(kf1, qf1, a, 0, 0, 0);
                s[sb] = a;
            }
            if (st >= dstile) {   // causal mask: s_global > t_global
                #pragma unroll
                for (int sb = 0; sb < 4; sb++)
                    #pragma unroll
                    for (int rg = 0; rg < 4; rg++) {
                        const int sg = st * 64 + sb * 16 + quad * 4 + rg;
                        if (sg > tg) s[sb][rg] = -1e30f;
                    }
            }
            // online softmax (exp2 domain), per-lane: 16 scores for q-row tg
            float rm = -1e30f;
            #pragma unroll
            for (int sb = 0; sb < 4; sb++)
                #pragma unroll
                for (int rg = 0; rg < 4; rg++) rm = fmaxf(rm, s[sb][rg]);
            rm = fmaxf(rm, __shfl_xor(rm, 16));
            rm = fmaxf(rm, __shfl_xor(rm, 32));
            // T13 defer-max: skip O/l rescale unless max grew past threshold
            if (!__all(rm <= m_i + 8.f)) {
                const float mn    = fmaxf(m_i, rm);
                const float alpha = __builtin_amdgcn_exp2f(m_i - mn);
                l_i *= alpha;
                #pragma unroll
                for (int db = 0; db < 4; db++)
                    #pragma unroll
                    for (int rg = 0; rg < 4; rg++) o[db][rg] *= alpha;
                m_i = mn;
            }
            float rs = 0.f;
            #pragma unroll
            for (int sb = 0; sb < 4; sb++)
                #pragma unroll
                for (int rg = 0; rg < 4; rg++) {
                    const float p = __builtin_amdgcn_exp2f(s[sb][rg] - m_i);
                    s[sb][rg] = p;
                    rs += p;
                }
            rs += __shfl_xor(rs, 16);
            rs += __shfl_xor(rs, 32);
            l_i += rs;

            // P^T -> LDS as [t][s]; packed pairs via v_cvt_pk_bf16_f32 (T12)
            #pragma unroll
            for (int sb = 0; sb < 4; sb++) {
                uint32x2 pk2;
                pk2[0] = cvtpk(s[sb][0], s[sb][1]);
                pk2[1] = cvtpk(s[sb][2], s[sb][3]);
                *(uint32x2*)(pwr + sb * 32 + quad * 8) = pk2;
            }

            // O^T += V^T P^T: A = Vs row d [k=s], B = Ps row t [k=s]
            const bf16x8 pa0 = *(const bf16x8*)(pwr + quad * 16);
            const bf16x8 pa1 = *(const bf16x8*)(pwr + 64 + quad * 16);
            #pragma unroll
            for (int db = 0; db < 4; db++) {
                const bf16x8 vf0 = *(const bf16x8*)(vs + off16[db][0]);
                const bf16x8 vf1 = *(const bf16x8*)(vs + off16[db][1]);
                o[db] = __builtin_amdgcn_mfma_f32_16x16x32_bf16(vf0, pa0, o[db], 0, 0, 0);
                o[db] = __builtin_amdgcn_mfma_f32_16x16x32_bf16(vf1, pa1, o[db], 0, 0, 0);
            }
        }
        __syncthreads();   // drains vmcnt (prefetch landed) + protects buffers
        cur ^= 1;
    }

    // epilogue: O^T lane owns q-row tg; d = db*16 + quad*4 + rg (4 consecutive)
    const int h = nh & 15;
    const float inv = 1.f / l_i;
    ushort_t* yrow = y_ws + ((size_t)(n * T_ + tg)) * 1024 + h * 64;
    #pragma unroll
    for (int db = 0; db < 4; db++) {
        uint32x2 pk2;
        pk2[0] = cvtpk(o[db][0] * inv, o[db][1] * inv);
        pk2[1] = cvtpk(o[db][2] * inv, o[db][3] * inv);
        *(uint32x2*)(yrow + db * 16 + quad * 4) = pk2;
    }
}

// ---------------------------------------------------------------------------
extern "C" void kernel_launch(void* const* d_in, const int* in_sizes, int n_in,
                              void* d_out, int out_size, void* d_ws, size_t ws_size,
                              hipStream_t stream) {
    (void)in_sizes; (void)n_in; (void)out_size; (void)ws_size;
    const float* x  = (const float*)d_in[0];
    const float* wq = (const float*)d_in[1];
    const float* wk = (const float*)d_in[2];
    const float* wv = (const float*)d_in[3];
    const float* wo = (const float*)d_in[4];
    char* ws = (char*)d_ws;
    const size_t MB = (size_t)1024 * 1024;
    ushort_t* x_bf  = (ushort_t*)(ws);            // 16 MB; reused as y after attn
    ushort_t* q_ws  = (ushort_t*)(ws + 16 * MB);  // 16 MB
    ushort_t* k_ws  = (ushort_t*)(ws + 32 * MB);  // 16 MB
    ushort_t* vt_ws = (ushort_t*)(ws + 48 * MB);  // 16 MB
    ushort_t* wcat  = (ushort_t*)(ws + 64 * MB);  // 6 MB  [3072][1024]
    ushort_t* wot   = (ushort_t*)(ws + 70 * MB);  // 2 MB  [1024(c)][1024(hd)]
    ushort_t* y_ws  = x_bf;                       // safe: attn never reads x_bf
    float*    outp  = (float*)d_out;              // f32 output

    cvt_f32_bf16<<<dim3(8192), dim3(256), 0, stream>>>(x, x_bf);
    cvt3_f32_bf16<<<dim3(3072), dim3(256), 0, stream>>>(wq, wk, wv, wcat);
    transpose_wo<<<dim3(256), dim3(256), 0, stream>>>(wo, wot);
    gemm8<0><<<dim3(32, 24), dim3(512), 0, stream>>>(x_bf, wcat, q_ws, k_ws, vt_ws, nullptr);
    attn<<<dim3(1024), dim3(512), 0, stream>>>(q_ws, k_ws, vt_ws, y_ws);
    gemm8<1><<<dim3(32, 8), dim3(512), 0, stream>>>(y_ws, wot, nullptr, nullptr, nullptr, outp);
}

// Round 6
// 254.265 us; speedup vs baseline: 1.0188x; 1.0188x over previous
//
#include <hip/hip_runtime.h>
#include <stdint.h>

#define B_ 4
#define T_ 2048
#define C_ 1024
#define H_ 16
#define D_ 64
#define M_ (B_*T_)      /* 8192 */
#define K_ C_           /* 1024 */

typedef unsigned short ushort_t;
typedef __bf16 bf16x8 __attribute__((ext_vector_type(8)));
typedef float  float4_ __attribute__((ext_vector_type(4)));
typedef ushort_t ushort4_ __attribute__((ext_vector_type(4)));
typedef uint32_t uint32x2 __attribute__((ext_vector_type(2)));

__device__ __forceinline__ ushort_t f2bf(float f) {
    union { float f; uint32_t u; } c; c.f = f;
    uint32_t u = c.u;
    uint32_t r = (u + 0x7FFFu + ((u >> 16) & 1u)) >> 16;
    return (ushort_t)r;
}
__device__ __forceinline__ float4_ f4zero() { float4_ z; z[0]=0.f; z[1]=0.f; z[2]=0.f; z[3]=0.f; return z; }

// packed f32x2 -> bf16x2 (single HW instr; no builtin on gfx950 — T12 recipe)
__device__ __forceinline__ uint32_t cvtpk(float a, float b) {
    uint32_t r;
    asm("v_cvt_pk_bf16_f32 %0, %1, %2" : "=v"(r) : "v"(a), "v"(b));
    return r;
}

// async global->LDS, 16B per lane; LDS dest must be wave-uniform base + lane*16
#define GLDS16(gptr, lptr) \
    __builtin_amdgcn_global_load_lds((const __attribute__((address_space(1))) uint32_t*)(gptr), \
                                     (__attribute__((address_space(3))) uint32_t*)(lptr), 16, 0, 0)

// raw barrier / counted waits (NEVER __syncthreads in the pipelined GEMM —
// it drains vmcnt(0) and kills the in-flight prefetch)
#define BARRIER() asm volatile("s_barrier" ::: "memory")
#define VMCNT(n)  asm volatile("s_waitcnt vmcnt(" #n ")" ::: "memory")

// ---------------------------------------------------------------------------
// f32 -> bf16 conversion, 4 elements/thread
// ---------------------------------------------------------------------------
__global__ __launch_bounds__(256) void cvt_f32_bf16(const float* __restrict__ src,
                                                    ushort_t* __restrict__ dst) {
    const int i = (blockIdx.x * 256 + threadIdx.x) * 4;
    float4_ v = *(const float4_*)(src + i);
    ushort4_ o;
    #pragma unroll
    for (int e = 0; e < 4; e++) o[e] = f2bf(v[e]);
    *(ushort4_*)(dst + i) = o;
}

// fused 3-matrix cvt: wq|wk|wv (1M elements each) -> wcat [3072][1024]
__global__ __launch_bounds__(256) void cvt3_f32_bf16(const float* __restrict__ s0,
                                                     const float* __restrict__ s1,
                                                     const float* __restrict__ s2,
                                                     ushort_t* __restrict__ dst) {
    const int b = blockIdx.x;                       // 0..3071
    const float* src = (b < 1024) ? s0 : (b < 2048) ? s1 : s2;
    const int off = (b & 1023) * 1024 + threadIdx.x * 4;
    float4_ v = *(const float4_*)(src + off);
    ushort4_ o;
    #pragma unroll
    for (int e = 0; e < 4; e++) o[e] = f2bf(v[e]);
    *(ushort4_*)(dst + (size_t)b * 1024 + threadIdx.x * 4) = o;
}

// ---------------------------------------------------------------------------
// w_o f32 [1024(hd)][1024(c)] -> wot bf16 [1024(c)][1024(hd)]
// ---------------------------------------------------------------------------
__global__ __launch_bounds__(256) void transpose_wo(const float* __restrict__ wo,
                                                    ushort_t* __restrict__ wot) {
    __shared__ ushort_t tile[64][65];
    const int c0 = (blockIdx.x & 15) * 64;
    const int r0 = (blockIdx.x >> 4) * 64;   // hd tile base
    const int tid = threadIdx.x;
    const int row = tid >> 2;                // 64 rows, 4 threads/row
    const int col = (tid & 3) * 16;
    #pragma unroll
    for (int r = 0; r < 4; r++) {
        float4_ v = *(const float4_*)(wo + (size_t)(r0 + row) * 1024 + c0 + col + r * 4);
        #pragma unroll
        for (int e = 0; e < 4; e++) tile[row][col + r * 4 + e] = f2bf(v[e]);
    }
    __syncthreads();
    #pragma unroll
    for (int r = 0; r < 2; r++) {
        bf16x8 v;
        #pragma unroll
        for (int e = 0; e < 8; e++) v[e] = __builtin_bit_cast(__bf16, tile[col + r * 8 + e][row]);
        *(bf16x8*)(wot + (size_t)(c0 + row) * 1024 + r0 + col + r * 8) = v;
    }
}

// ---------------------------------------------------------------------------
// Deep-prefetch pipelined GEMM: C[M x N] = A[M x K] * Bt[N x K]^T
//   BM=256, BN=128, BK=64, 8 waves (4M x 2N), per-wave 64x64 (acc[4][4]).
// ROUND-5 FIX: r5's half-tile double-buffer had ~1-phase prefetch depth
//   (B staged in P1, gated at END of P1 -> every gate exposed L2 latency;
//   MfmaUtil 22%). Now: 3 FULL buffers (A 32KB + B 16KB each = 144 KB LDS);
//   while computing tile t, stage ALL of tile t+2 (6 glds) into buf (t+2)%3.
//   Gate at end of tile t = vmcnt(6): drains t+1's 6 loads (issued during
//   t-1, in flight ~4 phases ~600-1000 cyc), leaves t+2's flying.
// Per tile (2 phases):
//   Pa: ds_read A mi0-1 + B (12xb128) | stage 3 chunks | BAR | 16 MFMA | BAR
//   Pb: ds_read A mi2-3  (4xb128)     | stage 3 chunks | BAR | 16 MFMA | GATE | BAR
// T2 XOR swizzle: linear glds dest + inverse-swizzled global source + swizzled
//   ds_read (verified conflict-free in r5: SQ_LDS_BANK_CONFLICT = 0).
// ---------------------------------------------------------------------------
template<int MODE>
__global__ __launch_bounds__(512, 2)
void gemm8(const ushort_t* __restrict__ A,
           const ushort_t* __restrict__ Bt,
           ushort_t* __restrict__ q_ws, ushort_t* __restrict__ k_ws,
           ushort_t* __restrict__ vt_ws, float* __restrict__ outp)
{
    __shared__ __align__(16) ushort_t As3[3][256 * 64];  // [buf][row][64] 96 KB
    __shared__ __align__(16) ushort_t Bs3[3][128 * 64];  // [buf][row][64] 48 KB
    const int tid = threadIdx.x;
    const int m0 = blockIdx.x * 256;
    const int n0 = blockIdx.y * 128;
    const int L = tid & 63, wid = tid >> 6;
    const int wm = wid >> 1;          // 0..3 (M)
    const int wn = wid & 1;           // 0..1 (N)
    const int quad = L >> 4, lc = L & 15;

    // ---- staging addressing: 8 KB chunks (512 thr x 16 B = 64 rows x 128 B)
    // LDS dest linear; global SOURCE carries the inverse XOR swizzle (rule #21)
    const int loff = tid * 16;
    const int lr   = loff >> 7;                      // 0..63 within chunk
    const int sp   = ((loff >> 4) & 7) ^ (lr & 7);   // swizzled 16B slot
    size_t a_src[4], b_src[2];
    #pragma unroll
    for (int q = 0; q < 4; q++)
        a_src[q] = (size_t)(m0 + q * 64 + lr) * 2048 + sp * 16;
    #pragma unroll
    for (int q = 0; q < 2; q++)
        b_src[q] = (size_t)(n0 + q * 64 + lr) * 2048 + sp * 16;
    const char* Ag = (const char*)A;
    const char* Bg = (const char*)Bt;

#define SA(c, q, kt) GLDS16(Ag + a_src[q] + (size_t)(kt) * 128, (char*)As3[c] + (q) * 8192 + loff)
#define SB(c, q, kt) GLDS16(Bg + b_src[q] + (size_t)(kt) * 128, (char*)Bs3[c] + (q) * 8192 + loff)

    // ---- swizzled fragment read offsets (loop-invariant)
    int offA[4][2], offB[4][2];   // [mi][ks], [nj][ks]; row&7 == lc&7
    #pragma unroll
    for (int mi = 0; mi < 4; mi++)
        #pragma unroll
        for (int ks = 0; ks < 2; ks++) {
            const int row = wm * 64 + mi * 16 + lc;
            offA[mi][ks] = row * 128 + (((ks * 4 + quad) ^ (lc & 7)) << 4);
        }
    #pragma unroll
    for (int nj = 0; nj < 4; nj++)
        #pragma unroll
        for (int ks = 0; ks < 2; ks++) {
            const int row = wn * 64 + nj * 16 + lc;
            offB[nj][ks] = row * 128 + (((ks * 4 + quad) ^ (lc & 7)) << 4);
        }

    float4_ acc[4][4];
    #pragma unroll
    for (int i = 0; i < 4; i++)
        #pragma unroll
        for (int j = 0; j < 4; j++) acc[i][j] = f4zero();

    bf16x8 bfr[4][2];
    bf16x8 af[2][2];

#define LOAD_AF(c, mb) \
    _Pragma("unroll") for (int mi2_ = 0; mi2_ < 2; mi2_++) \
    _Pragma("unroll") for (int ks_ = 0; ks_ < 2; ks_++) \
        af[mi2_][ks_] = *(const bf16x8*)((const char*)As3[c] + offA[(mb) + mi2_][ks_]);
#define LOAD_BF(c) \
    _Pragma("unroll") for (int nj_ = 0; nj_ < 4; nj_++) \
    _Pragma("unroll") for (int ks_ = 0; ks_ < 2; ks_++) \
        bfr[nj_][ks_] = *(const bf16x8*)((const char*)Bs3[c] + offB[nj_][ks_]);
#define PHASE_MFMA(MB) \
    __builtin_amdgcn_s_setprio(1); \
    _Pragma("unroll") for (int mi2_ = 0; mi2_ < 2; mi2_++) \
    _Pragma("unroll") for (int nj_ = 0; nj_ < 4; nj_++) { \
        acc[(MB) + mi2_][nj_] = __builtin_amdgcn_mfma_f32_16x16x32_bf16(af[mi2_][0], bfr[nj_][0], acc[(MB) + mi2_][nj_], 0, 0, 0); \
        acc[(MB) + mi2_][nj_] = __builtin_amdgcn_mfma_f32_16x16x32_bf16(af[mi2_][1], bfr[nj_][1], acc[(MB) + mi2_][nj_], 0, 0, 0); \
    } \
    __builtin_amdgcn_s_setprio(0);

// one K-tile: c = buf of t, cn = buf of t+2, DO_STAGE in {0,1}
#define TILE(c, cn, t, DO_STAGE, GATE) \
    LOAD_AF(c, 0); \
    LOAD_BF(c); \
    if (DO_STAGE) { SA(cn, 0, (t) + 2); SA(cn, 1, (t) + 2); SB(cn, 0, (t) + 2); } \
    BARRIER(); \
    PHASE_MFMA(0); \
    BARRIER(); \
    LOAD_AF(c, 2); \
    if (DO_STAGE) { SA(cn, 2, (t) + 2); SA(cn, 3, (t) + 2); SB(cn, 1, (t) + 2); } \
    BARRIER(); \
    PHASE_MFMA(2); \
    GATE; \
    BARRIER();

    // ---- prologue: stage tiles 0 and 1 fully (12 loads); drain tile0's 6
    SA(0, 0, 0); SA(0, 1, 0); SA(0, 2, 0); SA(0, 3, 0); SB(0, 0, 0); SB(0, 1, 0);
    SA(1, 0, 1); SA(1, 1, 1); SA(1, 2, 1); SA(1, 3, 1); SB(1, 0, 1); SB(1, 1, 1);
    VMCNT(6);
    BARRIER();

    // ---- 16 K-tiles; t=0..11 unrolled x3 (static buf indices), 12..15 peeled
    for (int tb = 0; tb < 4; tb++) {
        const int t0 = tb * 3;
        TILE(0, 2, t0,     1, VMCNT(6));
        TILE(1, 0, t0 + 1, 1, VMCNT(6));
        TILE(2, 1, t0 + 2, 1, VMCNT(6));
    }
    TILE(0, 2, 12, 1, VMCNT(6));   // stages tile 14 -> buf2
    TILE(1, 0, 13, 1, VMCNT(6));   // stages tile 15 -> buf0; drains t14's
    TILE(2, 0, 14, 0, VMCNT(0));   // no stage; drains t15's 6
    TILE(0, 0, 15, 0, );           // final tile, no gate needed

#undef TILE
#undef LOAD_AF
#undef LOAD_BF
#undef PHASE_MFMA
#undef SA
#undef SB

    // ---- epilogue: C/D layout col=lane&15, row=quad*4+reg (m89-verified)
    const int mat = n0 >> 10;          // MODE 0: which of q/k/v
    const int nb  = n0 & 1023;
    const int wr  = wm * 64;
    const int wc  = wn * 64;
    #pragma unroll
    for (int i = 0; i < 4; i++) {
        #pragma unroll
        for (int j = 0; j < 4; j++) {
            #pragma unroll
            for (int rg = 0; rg < 4; rg++) {
                const int mg = m0 + wr + i * 16 + quad * 4 + rg;
                const float v = acc[i][j][rg];
                if (MODE == 1) {
                    const int cg = n0 + wc + j * 16 + lc;
                    outp[(size_t)mg * 1024 + cg] = v;          // f32 store
                } else {
                    const int ln = nb + wc + j * 16 + lc;
                    const int h = ln >> 6, d = ln & 63;
                    const int n = mg >> 11, t = mg & 2047;
                    const int nh = n * H_ + h;
                    // 0.125 * log2(e): softmax computed with exp2 (saves 1 mul/score)
                    if (mat == 0)      q_ws [((size_t)nh * T_ + t) * 64 + d] = f2bf(v * 0.18033688011112042f);
                    else if (mat == 1) k_ws [((size_t)nh * T_ + t) * 64 + d] = f2bf(v);
                    else               vt_ws[((size_t)nh * 64 + d) * T_ + t] = f2bf(v);
                }
            }
        }
    }
}

// ---------------------------------------------------------------------------
// MFMA flash attention, transposed formulation (round-3, validated):
//   S^T = K Q^T ; O^T = V^T P^T ; per-lane scalar softmax state (exp2 domain).
//   Global heavy-first dispatch + XCD-local nh mapping.
// ---------------------------------------------------------------------------
#define KP 72   /* Ps padded row pitch, elements (P path only) */

__global__ __launch_bounds__(512)
void attn(const ushort_t* __restrict__ q_ws, const ushort_t* __restrict__ k_ws,
          const ushort_t* __restrict__ vt_ws, ushort_t* __restrict__ y_ws)
{
    __shared__ __align__(16) ushort_t Ks[2][64 * 64];   // [s][d] 128B pitch, swizzled
    __shared__ __align__(16) ushort_t Vs[2][64 * 64];   // [d][s] 128B pitch, swizzled
    __shared__ __align__(16) ushort_t Ps[8][16 * KP];   // per-wave P^T as [t][s]
    const int tid  = threadIdx.x;
    const int L    = tid & 63;
    const int w    = tid >> 6;           // 0..7
    const int quad = L >> 4, lc = L & 15;
    const int bid  = blockIdx.x;
    const int qt   = 15 - (bid >> 6);    // GLOBAL heavy-first: qt=15 blocks first
    const int nh   = bid & 63;           // bid%8 == nh%8 -> XCD-local K/V
    const int n    = nh >> 4;
    const int tq0  = qt * 128 + w * 16;
    const int tg   = tq0 + lc;           // this lane's q-row
    const int nt   = 2 * qt + 2;         // K/V 64-tiles this block touches
    const int dstile = tq0 >> 6;         // first tile needing the causal mask

    // Q fragments (B-operand layout [n=t=lc][k=d=quad*8+j]):
    const ushort_t* qbase = q_ws + ((size_t)nh * T_ + tq0) * 64;
    const bf16x8 qf0 = *(const bf16x8*)(qbase + (size_t)lc * 64 + quad * 8);
    const bf16x8 qf1 = *(const bf16x8*)(qbase + (size_t)lc * 64 + quad * 8 + 32);

    float m_i = -1e30f, l_i = 0.f;       // per-lane scalars (q-row tg), log2 domain
    float4_ o[4];                        // O^T C-layout: col=t (lane), row=d
    #pragma unroll
    for (int r = 0; r < 4; r++) o[r] = f4zero();

    const char* kbase = (const char*)(k_ws  + (size_t)nh * T_ * 64);   // [t][d]
    const char* vbase = (const char*)(vt_ws + (size_t)nh * 64 * T_);   // [d][t]
    char* pwr = (char*)Ps[w] + lc * (KP * 2);

    // staging: 512 threads x 16B = one 8KB tile per glds instruction.
    const int ldsoff = tid * 16;                 // linear byte offset in 8KB buffer
    const int srow   = ldsoff >> 7;              // 0..63
    const int sslot  = (ldsoff >> 4) & 7;
    const int sgs    = sslot ^ (srow & 7);       // inverse swizzle on SOURCE
    const size_t kgo = (size_t)srow * 128 + sgs * 16;
    const size_t vgo = (size_t)srow * (T_ * 2) + sgs * 16;

    // loop-invariant swizzled read offsets (rows b*16+lc, 16B slots quad/quad+4)
    int off16[4][2];
    #pragma unroll
    for (int b = 0; b < 4; b++) {
        const int row = b * 16 + lc;
        const int r7  = lc & 7;                  // (b*16+lc)&7 == lc&7
        off16[b][0] = row * 128 + ((quad ^ r7) << 4);
        off16[b][1] = row * 128 + (((quad + 4) ^ r7) << 4);
    }

    auto STAGE = [&](int st, int b) {
        GLDS16(kbase + (size_t)st * 8192 + kgo, (char*)Ks[b] + ldsoff);
        GLDS16(vbase + (size_t)st * 128  + vgo, (char*)Vs[b] + ldsoff);
    };

    STAGE(0, 0);
    __syncthreads();                      // drains vmcnt(0): buf0 staged
    int cur = 0;

    for (int st = 0; st < nt; st++) {
        if (st + 1 < nt) STAGE(st + 1, cur ^ 1);   // prefetch overlaps compute
        // wave-uniform skip of fully-masked final tile (lower-half waves)
        if (st * 64 <= tq0 + 15) {
            const char* ks = (const char*)Ks[cur];
            const char* vs = (const char*)Vs[cur];

            // S^T = K Q^T: 4 s-blocks of 16; D[s][t]: row=quad*4+rg, col=lc
            float4_ s[4];
            #pragma unroll
            for (int sb = 0; sb < 4; sb++) {
                const bf16x8 kf0 = *(const bf16x8*)(ks + off16[sb][0]);
                const bf16x8 kf1 = *(const bf16x8*)(ks + off16[sb][1]);
                float4_ a = f4zero();
                a = __builtin_amdgcn_mfma_f32_16x16x32_bf16(kf0, qf0, a, 0, 0, 0);
                a = __builtin_amdgcn_mfma_f32_16x16x32_bf16(kf1, qf1, a, 0, 0, 0);
                s[sb] = a;
            }
            if (st >= dstile) {   // causal mask: s_global > t_global
                #pragma unroll
                for (int sb = 0; sb < 4; sb++)
                    #pragma unroll
                    for (int rg = 0; rg < 4; rg++) {
                        const int sg = st * 64 + sb * 16 + quad * 4 + rg;
                        if (sg > tg) s[sb][rg] = -1e30f;
                    }
            }
            // online softmax (exp2 domain), per-lane: 16 scores for q-row tg
            float rm = -1e30f;
            #pragma unroll
            for (int sb = 0; sb < 4; sb++)
                #pragma unroll
                for (int rg = 0; rg < 4; rg++) rm = fmaxf(rm, s[sb][rg]);
            rm = fmaxf(rm, __shfl_xor(rm, 16));
            rm = fmaxf(rm, __shfl_xor(rm, 32));
            // T13 defer-max: skip O/l rescale unless max grew past threshold
            if (!__all(rm <= m_i + 8.f)) {
                const float mn    = fmaxf(m_i, rm);
                const float alpha = __builtin_amdgcn_exp2f(m_i - mn);
                l_i *= alpha;
                #pragma unroll
                for (int db = 0; db < 4; db++)
                    #pragma unroll
                    for (int rg = 0; rg < 4; rg++) o[db][rg] *= alpha;
                m_i = mn;
            }
            float rs = 0.f;
            #pragma unroll
            for (int sb = 0; sb < 4; sb++)
                #pragma unroll
                for (int rg = 0; rg < 4; rg++) {
                    const float p = __builtin_amdgcn_exp2f(s[sb][rg] - m_i);
                    s[sb][rg] = p;
                    rs += p;
                }
            rs += __shfl_xor(rs, 16);
            rs += __shfl_xor(rs, 32);
            l_i += rs;

            // P^T -> LDS as [t][s]; packed pairs via v_cvt_pk_bf16_f32 (T12)
            #pragma unroll
            for (int sb = 0; sb < 4; sb++) {
                uint32x2 pk2;
                pk2[0] = cvtpk(s[sb][0], s[sb][1]);
                pk2[1] = cvtpk(s[sb][2], s[sb][3]);
                *(uint32x2*)(pwr + sb * 32 + quad * 8) = pk2;
            }

            // O^T += V^T P^T: A = Vs row d [k=s], B = Ps row t [k=s]
            const bf16x8 pa0 = *(const bf16x8*)(pwr + quad * 16);
            const bf16x8 pa1 = *(const bf16x8*)(pwr + 64 + quad * 16);
            #pragma unroll
            for (int db = 0; db < 4; db++) {
                const bf16x8 vf0 = *(const bf16x8*)(vs + off16[db][0]);
                const bf16x8 vf1 = *(const bf16x8*)(vs + off16[db][1]);
                o[db] = __builtin_amdgcn_mfma_f32_16x16x32_bf16(vf0, pa0, o[db], 0, 0, 0);
                o[db] = __builtin_amdgcn_mfma_f32_16x16x32_bf16(vf1, pa1, o[db], 0, 0, 0);
            }
        }
        __syncthreads();   // drains vmcnt (prefetch landed) + protects buffers
        cur ^= 1;
    }

    // epilogue: O^T lane owns q-row tg; d = db*16 + quad*4 + rg (4 consecutive)
    const int h = nh & 15;
    const float inv = 1.f / l_i;
    ushort_t* yrow = y_ws + ((size_t)(n * T_ + tg)) * 1024 + h * 64;
    #pragma unroll
    for (int db = 0; db < 4; db++) {
        uint32x2 pk2;
        pk2[0] = cvtpk(o[db][0] * inv, o[db][1] * inv);
        pk2[1] = cvtpk(o[db][2] * inv, o[db][3] * inv);
        *(uint32x2*)(yrow + db * 16 + quad * 4) = pk2;
    }
}

// ---------------------------------------------------------------------------
extern "C" void kernel_launch(void* const* d_in, const int* in_sizes, int n_in,
                              void* d_out, int out_size, void* d_ws, size_t ws_size,
                              hipStream_t stream) {
    (void)in_sizes; (void)n_in; (void)out_size; (void)ws_size;
    const float* x  = (const float*)d_in[0];
    const float* wq = (const float*)d_in[1];
    const float* wk = (const float*)d_in[2];
    const float* wv = (const float*)d_in[3];
    const float* wo = (const float*)d_in[4];
    char* ws = (char*)d_ws;
    const size_t MB = (size_t)1024 * 1024;
    ushort_t* x_bf  = (ushort_t*)(ws);            // 16 MB; reused as y after attn
    ushort_t* q_ws  = (ushort_t*)(ws + 16 * MB);  // 16 MB
    ushort_t* k_ws  = (ushort_t*)(ws + 32 * MB);  // 16 MB
    ushort_t* vt_ws = (ushort_t*)(ws + 48 * MB);  // 16 MB
    ushort_t* wcat  = (ushort_t*)(ws + 64 * MB);  // 6 MB  [3072][1024]
    ushort_t* wot   = (ushort_t*)(ws + 70 * MB);  // 2 MB  [1024(c)][1024(hd)]
    ushort_t* y_ws  = x_bf;                       // safe: attn never reads x_bf
    float*    outp  = (float*)d_out;              // f32 output

    cvt_f32_bf16<<<dim3(8192), dim3(256), 0, stream>>>(x, x_bf);
    cvt3_f32_bf16<<<dim3(3072), dim3(256), 0, stream>>>(wq, wk, wv, wcat);
    transpose_wo<<<dim3(256), dim3(256), 0, stream>>>(wo, wot);
    gemm8<0><<<dim3(32, 24), dim3(512), 0, stream>>>(x_bf, wcat, q_ws, k_ws, vt_ws, nullptr);
    attn<<<dim3(1024), dim3(512), 0, stream>>>(q_ws, k_ws, vt_ws, y_ws);
    gemm8<1><<<dim3(32, 8), dim3(512), 0, stream>>>(y_ws, wot, nullptr, nullptr, nullptr, outp);
}

// Round 7
// 253.080 us; speedup vs baseline: 1.0235x; 1.0047x over previous
//
#include <hip/hip_runtime.h>
#include <stdint.h>

#define B_ 4
#define T_ 2048
#define C_ 1024
#define H_ 16
#define D_ 64
#define M_ (B_*T_)      /* 8192 */
#define K_ C_           /* 1024 */

typedef unsigned short ushort_t;
typedef __bf16 bf16x8 __attribute__((ext_vector_type(8)));
typedef float  float4_ __attribute__((ext_vector_type(4)));
typedef ushort_t ushort4_ __attribute__((ext_vector_type(4)));
typedef uint32_t uint32x2 __attribute__((ext_vector_type(2)));

__device__ __forceinline__ ushort_t f2bf(float f) {
    union { float f; uint32_t u; } c; c.f = f;
    uint32_t u = c.u;
    uint32_t r = (u + 0x7FFFu + ((u >> 16) & 1u)) >> 16;
    return (ushort_t)r;
}
__device__ __forceinline__ float4_ f4zero() { float4_ z; z[0]=0.f; z[1]=0.f; z[2]=0.f; z[3]=0.f; return z; }

// packed f32x2 -> bf16x2 (single HW instr; no builtin on gfx950 — T12 recipe)
__device__ __forceinline__ uint32_t cvtpk(float a, float b) {
    uint32_t r;
    asm("v_cvt_pk_bf16_f32 %0, %1, %2" : "=v"(r) : "v"(a), "v"(b));
    return r;
}

// async global->LDS, 16B per lane; LDS dest must be wave-uniform base + lane*16
#define GLDS16(gptr, lptr) \
    __builtin_amdgcn_global_load_lds((const __attribute__((address_space(1))) uint32_t*)(gptr), \
                                     (__attribute__((address_space(3))) uint32_t*)(lptr), 16, 0, 0)

// ---------------------------------------------------------------------------
// f32 -> bf16 conversion, 4 elements/thread
// ---------------------------------------------------------------------------
__global__ __launch_bounds__(256) void cvt_f32_bf16(const float* __restrict__ src,
                                                    ushort_t* __restrict__ dst) {
    const int i = (blockIdx.x * 256 + threadIdx.x) * 4;
    float4_ v = *(const float4_*)(src + i);
    ushort4_ o;
    #pragma unroll
    for (int e = 0; e < 4; e++) o[e] = f2bf(v[e]);
    *(ushort4_*)(dst + i) = o;
}

// ---------------------------------------------------------------------------
// fused weight prep (one launch, saves a kernel-launch gap):
//   blocks 0..3071:  wq|wk|wv f32 -> wcat bf16 [3072][1024]
//   blocks 3072..3327: w_o f32 [1024(hd)][1024(c)] -> wot bf16 [1024(c)][1024(hd)]
// ---------------------------------------------------------------------------
__global__ __launch_bounds__(256) void prep_w(const float* __restrict__ s0,
                                              const float* __restrict__ s1,
                                              const float* __restrict__ s2,
                                              ushort_t* __restrict__ dst,
                                              const float* __restrict__ wo,
                                              ushort_t* __restrict__ wot) {
    __shared__ ushort_t tile[64][65];
    const int b = blockIdx.x;
    const int tid = threadIdx.x;
    if (b < 3072) {
        const float* src = (b < 1024) ? s0 : (b < 2048) ? s1 : s2;
        const int off = (b & 1023) * 1024 + tid * 4;
        float4_ v = *(const float4_*)(src + off);
        ushort4_ o;
        #pragma unroll
        for (int e = 0; e < 4; e++) o[e] = f2bf(v[e]);
        *(ushort4_*)(dst + (size_t)b * 1024 + tid * 4) = o;
    } else {
        const int bb = b - 3072;                 // 0..255
        const int c0 = (bb & 15) * 64;
        const int r0 = (bb >> 4) * 64;           // hd tile base
        const int row = tid >> 2;                // 64 rows, 4 threads/row
        const int col = (tid & 3) * 16;
        #pragma unroll
        for (int r = 0; r < 4; r++) {
            float4_ v = *(const float4_*)(wo + (size_t)(r0 + row) * 1024 + c0 + col + r * 4);
            #pragma unroll
            for (int e = 0; e < 4; e++) tile[row][col + r * 4 + e] = f2bf(v[e]);
        }
        __syncthreads();
        #pragma unroll
        for (int r = 0; r < 2; r++) {
            bf16x8 v;
            #pragma unroll
            for (int e = 0; e < 8; e++) v[e] = __builtin_bit_cast(__bf16, tile[col + r * 8 + e][row]);
            *(bf16x8*)(wot + (size_t)(c0 + row) * 1024 + r0 + col + r * 8) = v;
        }
    }
}

// ---------------------------------------------------------------------------
// GEMM: C[M x N] = A[M x K] * Bt[N x K]^T  (bf16 in, fp32 acc)
// PROVEN r3 structure (88 us @ MODE 0): 128x128 tile, 2-barrier K-loop,
// global_load_lds width=16 staging. r5/r6 pipelined rewrites both regressed
// (92 / 110 us, MfmaUtil 22/18%) — reverted; 8-phase gains need the exact
// m201 schedule which did not reproduce here (matches m232's documented null).
// r6 delta kept: V^T epilogue packs 4 t-consecutive rg values into ushort4_
// (4x fewer store instrs / L2 txns on the 64-lane-scatter path).
// MODE 0: Bt = Wcat [3072 x 1024]; scatters Q (x 0.125*log2(e), exp2-domain
//         softmax), K [nh][t][d], V^T [nh][d][t]
// MODE 1: Bt = wot [1024 x 1024]; f32 store to d_out
// ---------------------------------------------------------------------------
template<int MODE>
__global__ __launch_bounds__(256)
void gemm_bt(const ushort_t* __restrict__ A,
             const ushort_t* __restrict__ Bt,
             ushort_t* __restrict__ q_ws, ushort_t* __restrict__ k_ws,
             ushort_t* __restrict__ vt_ws, float* __restrict__ outp)
{
    __shared__ __align__(16) ushort_t As[128 * 32];
    __shared__ __align__(16) ushort_t Bs[128 * 32];
    const int tid = threadIdx.x;
    const int m0 = blockIdx.x * 128;
    const int n0 = blockIdx.y * 128;

    const int L    = tid & 63;
    const int wid  = tid >> 6;
    const int wr   = (wid >> 1) * 64;
    const int wc   = (wid & 1) * 64;
    const int quad = L >> 4;
    const int lc   = L & 15;

    float4_ acc[4][4];
    #pragma unroll
    for (int i = 0; i < 4; i++)
        #pragma unroll
        for (int j = 0; j < 4; j++) acc[i][j] = f4zero();

    const int loff0 = wid * 1024 + L * 16;   // per-lane byte offset = wave-base + lane*16
    for (int k0 = 0; k0 < K_; k0 += 32) {
        __syncthreads();
        #pragma unroll
        for (int r = 0; r < 2; r++) {
            const int off = loff0 + r * 4096;
            const int row = off >> 6;    // 64 B per tile row (32 bf16)
            const int col = off & 63;    // byte col
            const char* ga = (const char*)A  + (size_t)(m0 + row) * (K_ * 2) + k0 * 2 + col;
            const char* gb = (const char*)Bt + (size_t)(n0 + row) * (K_ * 2) + k0 * 2 + col;
            GLDS16(ga, (char*)As + off);
            GLDS16(gb, (char*)Bs + off);
        }
        __syncthreads();
        bf16x8 af[4], bfr[4];
        #pragma unroll
        for (int i = 0; i < 4; i++) {
            const int m = wr + i * 16 + lc;
            af[i]  = *(const bf16x8*)((const char*)As + m * 64 + quad * 16);
            const int n = wc + i * 16 + lc;
            bfr[i] = *(const bf16x8*)((const char*)Bs + n * 64 + quad * 16);
        }
        #pragma unroll
        for (int i = 0; i < 4; i++)
            #pragma unroll
            for (int j = 0; j < 4; j++)
                acc[i][j] = __builtin_amdgcn_mfma_f32_16x16x32_bf16(af[i], bfr[j], acc[i][j], 0, 0, 0);
    }

    // epilogue: C/D layout col=lane&15, row=quad*4+reg (m89-verified)
    const int mat = n0 >> 10;          // MODE 0: which of q/k/v
    const int nb  = n0 & 1023;
    if (MODE == 1) {
        #pragma unroll
        for (int i = 0; i < 4; i++)
            #pragma unroll
            for (int j = 0; j < 4; j++)
                #pragma unroll
                for (int rg = 0; rg < 4; rg++) {
                    const int mg = m0 + wr + i * 16 + quad * 4 + rg;
                    const int cg = n0 + wc + j * 16 + lc;
                    outp[(size_t)mg * 1024 + cg] = acc[i][j][rg];     // f32 store
                }
    } else if (mat == 2) {
        // V^T [nh][d][t]: rg values are t-consecutive -> one ushort4_ per (i,j)
        #pragma unroll
        for (int i = 0; i < 4; i++) {
            const int mg0 = m0 + wr + i * 16 + quad * 4;
            const int n = mg0 >> 11, t0 = mg0 & 2047;
            #pragma unroll
            for (int j = 0; j < 4; j++) {
                const int ln = nb + wc + j * 16 + lc;
                const int h = ln >> 6, d = ln & 63;
                const int nh = n * H_ + h;
                ushort4_ pk;
                #pragma unroll
                for (int rg = 0; rg < 4; rg++) pk[rg] = f2bf(acc[i][j][rg]);
                *(ushort4_*)(vt_ws + ((size_t)nh * 64 + d) * T_ + t0) = pk;
            }
        }
    } else {
        // Q (x 0.125*log2(e): softmax computed with exp2) or K, [nh][t][d]
        const float scl = (mat == 0) ? 0.18033688011112042f : 1.0f;
        ushort_t* dstp  = (mat == 0) ? q_ws : k_ws;
        #pragma unroll
        for (int i = 0; i < 4; i++)
            #pragma unroll
            for (int j = 0; j < 4; j++)
                #pragma unroll
                for (int rg = 0; rg < 4; rg++) {
                    const int mg = m0 + wr + i * 16 + quad * 4 + rg;
                    const int ln = nb + wc + j * 16 + lc;
                    const int h = ln >> 6, d = ln & 63;
                    const int n = mg >> 11, t = mg & 2047;
                    const int nh = n * H_ + h;
                    dstp[((size_t)nh * T_ + t) * 64 + d] = f2bf(acc[i][j][rg] * scl);
                }
    }
}

// ---------------------------------------------------------------------------
// MFMA flash attention, transposed formulation (round-3, validated):
//   S^T = K Q^T ; O^T = V^T P^T ; per-lane scalar softmax state (exp2 domain).
//   Global heavy-first dispatch + XCD-local nh mapping.
// ---------------------------------------------------------------------------
#define KP 72   /* Ps padded row pitch, elements (P path only) */

__global__ __launch_bounds__(512)
void attn(const ushort_t* __restrict__ q_ws, const ushort_t* __restrict__ k_ws,
          const ushort_t* __restrict__ vt_ws, ushort_t* __restrict__ y_ws)
{
    __shared__ __align__(16) ushort_t Ks[2][64 * 64];   // [s][d] 128B pitch, swizzled
    __shared__ __align__(16) ushort_t Vs[2][64 * 64];   // [d][s] 128B pitch, swizzled
    __shared__ __align__(16) ushort_t Ps[8][16 * KP];   // per-wave P^T as [t][s]
    const int tid  = threadIdx.x;
    const int L    = tid & 63;
    const int w    = tid >> 6;           // 0..7
    const int quad = L >> 4, lc = L & 15;
    const int bid  = blockIdx.x;
    const int qt   = 15 - (bid >> 6);    // GLOBAL heavy-first: qt=15 blocks first
    const int nh   = bid & 63;           // bid%8 == nh%8 -> XCD-local K/V
    const int n    = nh >> 4;
    const int tq0  = qt * 128 + w * 16;
    const int tg   = tq0 + lc;           // this lane's q-row
    const int nt   = 2 * qt + 2;         // K/V 64-tiles this block touches
    const int dstile = tq0 >> 6;         // first tile needing the causal mask

    // Q fragments (B-operand layout [n=t=lc][k=d=quad*8+j]):
    const ushort_t* qbase = q_ws + ((size_t)nh * T_ + tq0) * 64;
    const bf16x8 qf0 = *(const bf16x8*)(qbase + (size_t)lc * 64 + quad * 8);
    const bf16x8 qf1 = *(const bf16x8*)(qbase + (size_t)lc * 64 + quad * 8 + 32);

    float m_i = -1e30f, l_i = 0.f;       // per-lane scalars (q-row tg), log2 domain
    float4_ o[4];                        // O^T C-layout: col=t (lane), row=d
    #pragma unroll
    for (int r = 0; r < 4; r++) o[r] = f4zero();

    const char* kbase = (const char*)(k_ws  + (size_t)nh * T_ * 64);   // [t][d]
    const char* vbase = (const char*)(vt_ws + (size_t)nh * 64 * T_);   // [d][t]
    char* pwr = (char*)Ps[w] + lc * (KP * 2);

    // staging: 512 threads x 16B = one 8KB tile per glds instruction.
    const int ldsoff = tid * 16;                 // linear byte offset in 8KB buffer
    const int srow   = ldsoff >> 7;              // 0..63
    const int sslot  = (ldsoff >> 4) & 7;
    const int sgs    = sslot ^ (srow & 7);       // inverse swizzle on SOURCE
    const size_t kgo = (size_t)srow * 128 + sgs * 16;
    const size_t vgo = (size_t)srow * (T_ * 2) + sgs * 16;

    // loop-invariant swizzled read offsets (rows b*16+lc, 16B slots quad/quad+4)
    int off16[4][2];
    #pragma unroll
    for (int b = 0; b < 4; b++) {
        const int row = b * 16 + lc;
        const int r7  = lc & 7;                  // (b*16+lc)&7 == lc&7
        off16[b][0] = row * 128 + ((quad ^ r7) << 4);
        off16[b][1] = row * 128 + (((quad + 4) ^ r7) << 4);
    }

    auto STAGE = [&](int st, int b) {
        GLDS16(kbase + (size_t)st * 8192 + kgo, (char*)Ks[b] + ldsoff);
        GLDS16(vbase + (size_t)st * 128  + vgo, (char*)Vs[b] + ldsoff);
    };

    STAGE(0, 0);
    __syncthreads();                      // drains vmcnt(0): buf0 staged
    int cur = 0;

    for (int st = 0; st < nt; st++) {
        if (st + 1 < nt) STAGE(st + 1, cur ^ 1);   // prefetch overlaps compute
        // wave-uniform skip of fully-masked final tile (lower-half waves)
        if (st * 64 <= tq0 + 15) {
            const char* ks = (const char*)Ks[cur];
            const char* vs = (const char*)Vs[cur];

            // S^T = K Q^T: 4 s-blocks of 16; D[s][t]: row=quad*4+rg, col=lc
            float4_ s[4];
            #pragma unroll
            for (int sb = 0; sb < 4; sb++) {
                const bf16x8 kf0 = *(const bf16x8*)(ks + off16[sb][0]);
                const bf16x8 kf1 = *(const bf16x8*)(ks + off16[sb][1]);
                float4_ a = f4zero();
                a = __builtin_amdgcn_mfma_f32_16x16x32_bf16(kf0, qf0, a, 0, 0, 0);
                a = __builtin_amdgcn_mfma_f32_16x16x32_bf16(kf1, qf1, a, 0, 0, 0);
                s[sb] = a;
            }
            if (st >= dstile) {   // causal mask: s_global > t_global
                #pragma unroll
                for (int sb = 0; sb < 4; sb++)
                    #pragma unroll
                    for (int rg = 0; rg < 4; rg++) {
                        const int sg = st * 64 + sb * 16 + quad * 4 + rg;
                        if (sg > tg) s[sb][rg] = -1e30f;
                    }
            }
            // online softmax (exp2 domain), per-lane: 16 scores for q-row tg
            float rm = -1e30f;
            #pragma unroll
            for (int sb = 0; sb < 4; sb++)
                #pragma unroll
                for (int rg = 0; rg < 4; rg++) rm = fmaxf(rm, s[sb][rg]);
            rm = fmaxf(rm, __shfl_xor(rm, 16));
            rm = fmaxf(rm, __shfl_xor(rm, 32));
            // T13 defer-max: skip O/l rescale unless max grew past threshold
            if (!__all(rm <= m_i + 8.f)) {
                const float mn    = fmaxf(m_i, rm);
                const float alpha = __builtin_amdgcn_exp2f(m_i - mn);
                l_i *= alpha;
                #pragma unroll
                for (int db = 0; db < 4; db++)
                    #pragma unroll
                    for (int rg = 0; rg < 4; rg++) o[db][rg] *= alpha;
                m_i = mn;
            }
            float rs = 0.f;
            #pragma unroll
            for (int sb = 0; sb < 4; sb++)
                #pragma unroll
                for (int rg = 0; rg < 4; rg++) {
                    const float p = __builtin_amdgcn_exp2f(s[sb][rg] - m_i);
                    s[sb][rg] = p;
                    rs += p;
                }
            rs += __shfl_xor(rs, 16);
            rs += __shfl_xor(rs, 32);
            l_i += rs;

            // P^T -> LDS as [t][s]; packed pairs via v_cvt_pk_bf16_f32 (T12)
            #pragma unroll
            for (int sb = 0; sb < 4; sb++) {
                uint32x2 pk2;
                pk2[0] = cvtpk(s[sb][0], s[sb][1]);
                pk2[1] = cvtpk(s[sb][2], s[sb][3]);
                *(uint32x2*)(pwr + sb * 32 + quad * 8) = pk2;
            }

            // O^T += V^T P^T: A = Vs row d [k=s], B = Ps row t [k=s]
            const bf16x8 pa0 = *(const bf16x8*)(pwr + quad * 16);
            const bf16x8 pa1 = *(const bf16x8*)(pwr + 64 + quad * 16);
            #pragma unroll
            for (int db = 0; db < 4; db++) {
                const bf16x8 vf0 = *(const bf16x8*)(vs + off16[db][0]);
                const bf16x8 vf1 = *(const bf16x8*)(vs + off16[db][1]);
                o[db] = __builtin_amdgcn_mfma_f32_16x16x32_bf16(vf0, pa0, o[db], 0, 0, 0);
                o[db] = __builtin_amdgcn_mfma_f32_16x16x32_bf16(vf1, pa1, o[db], 0, 0, 0);
            }
        }
        __syncthreads();   // drains vmcnt (prefetch landed) + protects buffers
        cur ^= 1;
    }

    // epilogue: O^T lane owns q-row tg; d = db*16 + quad*4 + rg (4 consecutive)
    const int h = nh & 15;
    const float inv = 1.f / l_i;
    ushort_t* yrow = y_ws + ((size_t)(n * T_ + tg)) * 1024 + h * 64;
    #pragma unroll
    for (int db = 0; db < 4; db++) {
        uint32x2 pk2;
        pk2[0] = cvtpk(o[db][0] * inv, o[db][1] * inv);
        pk2[1] = cvtpk(o[db][2] * inv, o[db][3] * inv);
        *(uint32x2*)(yrow + db * 16 + quad * 4) = pk2;
    }
}

// ---------------------------------------------------------------------------
extern "C" void kernel_launch(void* const* d_in, const int* in_sizes, int n_in,
                              void* d_out, int out_size, void* d_ws, size_t ws_size,
                              hipStream_t stream) {
    (void)in_sizes; (void)n_in; (void)out_size; (void)ws_size;
    const float* x  = (const float*)d_in[0];
    const float* wq = (const float*)d_in[1];
    const float* wk = (const float*)d_in[2];
    const float* wv = (const float*)d_in[3];
    const float* wo = (const float*)d_in[4];
    char* ws = (char*)d_ws;
    const size_t MB = (size_t)1024 * 1024;
    ushort_t* x_bf  = (ushort_t*)(ws);            // 16 MB; reused as y after attn
    ushort_t* q_ws  = (ushort_t*)(ws + 16 * MB);  // 16 MB
    ushort_t* k_ws  = (ushort_t*)(ws + 32 * MB);  // 16 MB
    ushort_t* vt_ws = (ushort_t*)(ws + 48 * MB);  // 16 MB
    ushort_t* wcat  = (ushort_t*)(ws + 64 * MB);  // 6 MB  [3072][1024]
    ushort_t* wot   = (ushort_t*)(ws + 70 * MB);  // 2 MB  [1024(c)][1024(hd)]
    ushort_t* y_ws  = x_bf;                       // safe: attn never reads x_bf
    float*    outp  = (float*)d_out;              // f32 output

    cvt_f32_bf16<<<dim3(8192), dim3(256), 0, stream>>>(x, x_bf);
    prep_w<<<dim3(3328), dim3(256), 0, stream>>>(wq, wk, wv, wcat, wo, wot);
    gemm_bt<0><<<dim3(64, 24), dim3(256), 0, stream>>>(x_bf, wcat, q_ws, k_ws, vt_ws, nullptr);
    attn<<<dim3(1024), dim3(512), 0, stream>>>(q_ws, k_ws, vt_ws, y_ws);
    gemm_bt<1><<<dim3(64, 8), dim3(256), 0, stream>>>(y_ws, wot, nullptr, nullptr, nullptr, outp);
}